// Round 3
// baseline (881.126 us; speedup 1.0000x reference)
//
#include <hip/hip_runtime.h>

#define NN 150000
#define NE 600000
#define NG 5000
#define H 128
#define NOFF (NN + 1)
#define NBLK 147   // ceil(150001 / 1024)
#define NSPLIT 64  // stats_part split factor
#define NTILE 9375 // NN / 16 (exact)
#define NBLOCKS 256
#define MAXT 5     // max tiles per wave (9375 / 2048 -> 4..5)

typedef short bf16x8 __attribute__((ext_vector_type(8)));
typedef float f32x4 __attribute__((ext_vector_type(4)));

__device__ __forceinline__ unsigned short f2bf(float f) {
    unsigned u = __builtin_bit_cast(unsigned, f);
    u += 0x7fffu + ((u >> 16) & 1u);
    return (unsigned short)(u >> 16);
}
__device__ __forceinline__ float bf2f(unsigned short u) {
    return __builtin_bit_cast(float, (unsigned)u << 16);
}
__device__ __forceinline__ float bflo(unsigned u) {
    return __builtin_bit_cast(float, u << 16);
}
__device__ __forceinline__ float bfhi(unsigned u) {
    return __builtin_bit_cast(float, u & 0xffff0000u);
}
__device__ __forceinline__ unsigned packbf(float lo, float hi) {
    return (unsigned)f2bf(lo) | ((unsigned)f2bf(hi) << 16);
}

// ---------- fused setup: zero deg + graph bounds + weight prepack + barrier init ----------
// W1/W2 fragments (m 0..7) use the PAIRED-PERMUTED column layout for the
// transposed-MFMA fused kernel: fragment f=2c+h, slot n -> col c*32+(n>>2)*8+h*4+(n&3).
// Wo1/Wo2 (m 8..10) keep the standard layout.
__global__ __launch_bounds__(256) void setup_k(const int* __restrict__ batch,
                                               const float* __restrict__ W1,
                                               const float* __restrict__ W2,
                                               const float* __restrict__ Wo1,
                                               const float* __restrict__ Wo2,
                                               int* __restrict__ deg,
                                               int* __restrict__ gstart,
                                               unsigned short* __restrict__ Wf,
                                               int* __restrict__ bar) {
    int b = blockIdx.x;
    if (b < 586) {
        int i = b * 256 + threadIdx.x;
        if (i < NN) {
            deg[i] = 0;
            int bt = batch[i];
            int prev = (i == 0) ? -1 : batch[i - 1];
            for (int g = prev + 1; g <= bt; g++) gstart[g] = i;
            if (i == NN - 1)
                for (int g = bt + 1; g <= NG; g++) gstart[g] = NN;
        }
        return;
    }
    int m = b - 586;
    if (m == 0 && threadIdx.x == 0) { bar[0] = 0; bar[1] = 0; }
    const float* W; int ld, col0;
    if (m < 4)       { W = W1 + m * 16384;       ld = 128; col0 = 0; }
    else if (m < 8)  { W = W2 + (m - 4) * 16384; ld = 128; col0 = 0; }
    else if (m == 8) { W = Wo1;                  ld = 128; col0 = 0; }
    else if (m == 9) { W = Wo2;                  ld = 256; col0 = 0; }
    else             { W = Wo2;                  ld = 256; col0 = 128; }
    unsigned short* dst = Wf + m * 16384;
    for (int flat = threadIdx.x; flat < 2048; flat += 256) {
        int c = flat >> 8, kk = (flat >> 6) & 3, lane = flat & 63;
        int ns = lane & 15;
        int n;
        if (m < 8) n = (c >> 1) * 32 + (ns >> 2) * 8 + (c & 1) * 4 + (ns & 3);
        else       n = col0 + c * 16 + ns;
        int k0 = kk * 32 + (lane >> 4) * 8;
        ushort4 lo, hi;
        lo.x = f2bf(W[(size_t)(k0 + 0) * ld + n]);
        lo.y = f2bf(W[(size_t)(k0 + 1) * ld + n]);
        lo.z = f2bf(W[(size_t)(k0 + 2) * ld + n]);
        lo.w = f2bf(W[(size_t)(k0 + 3) * ld + n]);
        hi.x = f2bf(W[(size_t)(k0 + 4) * ld + n]);
        hi.y = f2bf(W[(size_t)(k0 + 5) * ld + n]);
        hi.z = f2bf(W[(size_t)(k0 + 6) * ld + n]);
        hi.w = f2bf(W[(size_t)(k0 + 7) * ld + n]);
        *(ushort4*)&dst[flat * 8]     = lo;
        *(ushort4*)&dst[flat * 8 + 4] = hi;
    }
}

// ---------- CSR build ----------

__global__ __launch_bounds__(256) void hist_k(const int* __restrict__ ei,
                                              int* __restrict__ deg) {
    int e = blockIdx.x * 256 + threadIdx.x;
    if (e < NE) atomicAdd(&deg[ei[NE + e]], 1);
}

__global__ __launch_bounds__(256) void scan1_k(const int* __restrict__ deg,
                                               int* __restrict__ part,
                                               int* __restrict__ bsum) {
    __shared__ int ls[256];
    int tid = threadIdx.x;
    int base = blockIdx.x * 1024 + tid * 4;
    int v[4], s = 0;
#pragma unroll
    for (int j = 0; j < 4; j++) {
        int idx = base + j;
        v[j] = (idx < NN) ? deg[idx] : 0;
        s += v[j];
    }
    ls[tid] = s;
    __syncthreads();
    for (int off = 1; off < 256; off <<= 1) {
        int t2 = (tid >= off) ? ls[tid - off] : 0;
        __syncthreads();
        if (tid >= off) ls[tid] += t2;
        __syncthreads();
    }
    int run = ls[tid] - s;
#pragma unroll
    for (int j = 0; j < 4; j++) {
        int idx = base + j;
        if (idx < NOFF) part[idx] = run;
        run += v[j];
    }
    if (tid == 255) bsum[blockIdx.x] = ls[255];
}

__global__ __launch_bounds__(256) void scan2_k(int* __restrict__ bsum) {
    __shared__ int ls[256];
    int tid = threadIdx.x;
    int v = (tid < NBLK) ? bsum[tid] : 0;
    ls[tid] = v;
    __syncthreads();
    for (int off = 1; off < 256; off <<= 1) {
        int t2 = (tid >= off) ? ls[tid - off] : 0;
        __syncthreads();
        if (tid >= off) ls[tid] += t2;
        __syncthreads();
    }
    if (tid < NBLK) bsum[tid] = ls[tid] - v;
}

__global__ __launch_bounds__(256) void scan3_k(const int* __restrict__ part,
                                               const int* __restrict__ bsum,
                                               int* __restrict__ offsets,
                                               int* __restrict__ cursor) {
    int tid = threadIdx.x;
    int base = blockIdx.x * 1024 + tid * 4;
    int bs = bsum[blockIdx.x];
#pragma unroll
    for (int j = 0; j < 4; j++) {
        int idx = base + j;
        if (idx < NOFF) {
            int o = part[idx] + bs;
            offsets[idx] = o;
            if (idx < NN) cursor[idx] = o;
        }
    }
}

__global__ __launch_bounds__(256) void fill_k(const int* __restrict__ ei,
                                              int* __restrict__ cursor,
                                              int* __restrict__ adj) {
    int e = blockIdx.x * 256 + threadIdx.x;
    if (e < NE) {
        int p = atomicAdd(&cursor[ei[NE + e]], 1);
        if (p >= 0 && p < NE) adj[p] = ei[e];
    }
}

// ---------- the persistent fused kernel ----------
// 256 blocks x 512 threads. 100 KB static LDS forces exactly 1 block/CU, so all
// 256 blocks are co-resident by construction -> the spin grid-barrier is safe.
// Phases: encoder | 4x { stageW + gather->LDS-T->MFMA(m in regs)+stats | BAR |
// bn(coef from stats, apply to reg-m, h += relu(bn(m))) | BAR } | pool | BAR |
// gemm(pooled@Wo1) | BAR | outproj(@Wo2).
__device__ __forceinline__ void gbar(int* cnt, int* rel, int ph) {
    __syncthreads();
    if (threadIdx.x == 0) {
        __threadfence();   // agent release: writeback L2, order prior stores
        if (atomicAdd(cnt, 1) == NBLOCKS * ph - 1) {
            atomicExch(rel, ph);
        } else {
            while (atomicAdd(rel, 0) < ph) __builtin_amdgcn_s_sleep(8);
        }
        __threadfence();   // agent acquire: invalidate stale L1/L2 lines
    }
    __syncthreads();
}

__global__ __launch_bounds__(512, 2) void fused_k(
        const float* __restrict__ x, const float* __restrict__ Wn,
        const float* __restrict__ bn_b,
        const int* __restrict__ offsets, const int* __restrict__ adj,
        const float* __restrict__ eps, const float* __restrict__ b1,
        const float* __restrict__ gamma, const float* __restrict__ beta,
        const float* __restrict__ bo1, const float* __restrict__ bo2,
        const unsigned short* __restrict__ Wf,
        unsigned short* __restrict__ h, float* __restrict__ stats4,
        unsigned short* __restrict__ pooled, unsigned short* __restrict__ tB,
        const int* __restrict__ gstart, float* __restrict__ out,
        int* __restrict__ bar) {
    __shared__ short Wlds[32768];      // layer W1|W2 frags (64 KB), reused by Wo
    __shared__ short Tlds[8][2048];    // per-wave 16x128 bf16 transpose, XOR-swizzled
    __shared__ float bnls[256];
    __shared__ float bncf[256];        // a[0..127], b[128..255]

    int* cnt = bar;
    int* rel = bar + 1;
    int tid = threadIdx.x, b = blockIdx.x;
    int w = tid >> 6, lane = tid & 63, quad = lane >> 4, lr = lane & 15;
    int gw = b * 8 + w;                // 0..2047
    short* T = Tlds[w];

    // ---- phase 0: encoder + zero the 4 layer-private stats buffers ----
    {
        int g0 = b * 512 + tid;
        if (g0 < 4 * NSPLIT * 256) stats4[g0] = 0.f;
        for (int t = g0; t < NN * 32; t += NBLOCKS * 512) {
            int i = t >> 5, q = t & 31;
            float4 acc = ((const float4*)bn_b)[q];
#pragma unroll
            for (int k = 0; k < 6; k++) {
                float xv = x[i * 6 + k];
                float4 wv = ((const float4*)Wn)[k * 32 + q];
                acc.x += xv * wv.x; acc.y += xv * wv.y;
                acc.z += xv * wv.z; acc.w += xv * wv.w;
            }
            ushort4 o;
            o.x = f2bf(acc.x); o.y = f2bf(acc.y); o.z = f2bf(acc.z); o.w = f2bf(acc.w);
            ((ushort4*)h)[t] = o;
        }
    }
    gbar(cnt, rel, 1);

    // ---- 4 GIN layers ----
#pragma unroll 1
    for (int l = 0; l < 4; l++) {
        float* stL = stats4 + l * (NSPLIT * 256);
        // stage this layer's W1/W2 fragments (block-local)
        {
            const bf16x8* w1p = (const bf16x8*)(Wf + l * 16384);
            const bf16x8* w2p = (const bf16x8*)(Wf + (4 + l) * 16384);
#pragma unroll
            for (int i = 0; i < 4; i++) {
                int flat = i * 512 + tid;
                ((bf16x8*)Wlds)[flat] = w1p[flat];
                ((bf16x8*)Wlds)[2048 + flat] = w2p[flat];
            }
        }
        __syncthreads();
        const bf16x8* W1f = (const bf16x8*)Wlds;
        const bf16x8* W2f = (const bf16x8*)(Wlds + 16384);
        float e = 1.f + eps[l];

        // b1 in permuted order: b1p[2*kk+hh][r] = b1[kk*32 + quad*8 + hh*4 + r]
        float4 b1p[8];
#pragma unroll
        for (int c = 0; c < 4; c++) {
            b1p[c * 2]     = ((const float4*)(b1 + l * 128))[c * 8 + quad * 2];
            b1p[c * 2 + 1] = ((const float4*)(b1 + l * 128))[c * 8 + quad * 2 + 1];
        }

        float sls[32], sls2[32];
#pragma unroll
        for (int s = 0; s < 32; s++) { sls[s] = 0.f; sls2[s] = 0.f; }

        uint4 mp[MAXT][4];   // per-tile packed bf16 m (register-resident)

        // ---- gather + MLP per tile (no barrier needed between them) ----
#pragma unroll
        for (int k = 0; k < MAXT; k++) {
            int t = gw + k * 2048;
            if (t < NTILE) {
                const uint4* hp = (const uint4*)h;
                // gather 16 rows -> swizzled LDS T (quarter-wave per row, 4 rounds)
#pragma unroll
                for (int j = 0; j < 4; j++) {
                    int i = t * 16 + j * 4 + quad;
                    uint4 sv = hp[(size_t)i * 16 + lr];
                    float a0 = bflo(sv.x) * e, a1 = bfhi(sv.x) * e;
                    float a2 = bflo(sv.y) * e, a3 = bfhi(sv.y) * e;
                    float a4 = bflo(sv.z) * e, a5 = bfhi(sv.z) * e;
                    float a6 = bflo(sv.w) * e, a7 = bfhi(sv.w) * e;
                    float c0 = 0.f, c1 = 0.f, c2 = 0.f, c3 = 0.f;
                    float c4 = 0.f, c5 = 0.f, c6 = 0.f, c7 = 0.f;
                    int s0 = offsets[i], s1 = offsets[i + 1];
                    int kk = s0;
                    for (; kk + 1 < s1; kk += 2) {
                        int src0 = adj[kk], src1 = adj[kk + 1];
                        uint4 v0 = hp[(size_t)src0 * 16 + lr];
                        uint4 v1 = hp[(size_t)src1 * 16 + lr];
                        a0 += bflo(v0.x); a1 += bfhi(v0.x);
                        a2 += bflo(v0.y); a3 += bfhi(v0.y);
                        a4 += bflo(v0.z); a5 += bfhi(v0.z);
                        a6 += bflo(v0.w); a7 += bfhi(v0.w);
                        c0 += bflo(v1.x); c1 += bfhi(v1.x);
                        c2 += bflo(v1.y); c3 += bfhi(v1.y);
                        c4 += bflo(v1.z); c5 += bfhi(v1.z);
                        c6 += bflo(v1.w); c7 += bfhi(v1.w);
                    }
                    if (kk < s1) {
                        uint4 v = hp[(size_t)adj[kk] * 16 + lr];
                        a0 += bflo(v.x); a1 += bfhi(v.x);
                        a2 += bflo(v.y); a3 += bfhi(v.y);
                        a4 += bflo(v.z); a5 += bfhi(v.z);
                        a6 += bflo(v.w); a7 += bfhi(v.w);
                    }
                    a0 += c0; a1 += c1; a2 += c2; a3 += c3;
                    a4 += c4; a5 += c5; a6 += c6; a7 += c7;
                    uint4 o;
                    o.x = packbf(a0, a1); o.y = packbf(a2, a3);
                    o.z = packbf(a4, a5); o.w = packbf(a6, a7);
                    int rw = j * 4 + quad;
                    *(uint4*)&T[((rw << 7) | (lr * 8)) ^ ((rw & 7) << 3)] = o;
                }

                // phase 1: t = relu(agg @ W1 + b1), transposed MFMA
                f32x4 acc1[8];
#pragma unroll
                for (int f = 0; f < 8; f++) acc1[f] = (f32x4){0.f, 0.f, 0.f, 0.f};
#pragma unroll
                for (int kk = 0; kk < 4; kk++) {
                    bf16x8 af = *(const bf16x8*)&T[((lr << 7) | (kk * 32 + quad * 8)) ^ ((lr & 7) << 3)];
#pragma unroll
                    for (int f = 0; f < 8; f++)
                        acc1[f] = __builtin_amdgcn_mfma_f32_16x16x32_bf16(
                            W1f[(f * 4 + kk) * 64 + lane], af, acc1[f], 0, 0, 0);
                }
                bf16x8 tf[4];
#pragma unroll
                for (int kk = 0; kk < 4; kk++) {
#pragma unroll
                    for (int hh = 0; hh < 2; hh++) {
#pragma unroll
                        for (int r = 0; r < 4; r++) {
                            float v = fmaxf(acc1[2 * kk + hh][r] + b1p[2 * kk + hh][r], 0.f);
                            tf[kk][hh * 4 + r] = (short)f2bf(v);
                        }
                    }
                }
                // phase 2: m = t @ W2 (b2 cancels in BatchNorm)
                f32x4 acc2[8];
#pragma unroll
                for (int f = 0; f < 8; f++) acc2[f] = (f32x4){0.f, 0.f, 0.f, 0.f};
#pragma unroll
                for (int f = 0; f < 8; f++) {
                    acc2[f] = __builtin_amdgcn_mfma_f32_16x16x32_bf16(W2f[(f * 4 + 0) * 64 + lane], tf[0], acc2[f], 0, 0, 0);
                    acc2[f] = __builtin_amdgcn_mfma_f32_16x16x32_bf16(W2f[(f * 4 + 1) * 64 + lane], tf[1], acc2[f], 0, 0, 0);
                    acc2[f] = __builtin_amdgcn_mfma_f32_16x16x32_bf16(W2f[(f * 4 + 2) * 64 + lane], tf[2], acc2[f], 0, 0, 0);
                    acc2[f] = __builtin_amdgcn_mfma_f32_16x16x32_bf16(W2f[(f * 4 + 3) * 64 + lane], tf[3], acc2[f], 0, 0, 0);
                }
                // stats (pre-rounding) + pack m into registers
#pragma unroll
                for (int c = 0; c < 4; c++) {
                    f32x4 a = acc2[2 * c], bb = acc2[2 * c + 1];
#pragma unroll
                    for (int r = 0; r < 4; r++) {
                        sls[(2 * c) * 4 + r]      += a[r];
                        sls2[(2 * c) * 4 + r]     += a[r] * a[r];
                        sls[(2 * c + 1) * 4 + r]  += bb[r];
                        sls2[(2 * c + 1) * 4 + r] += bb[r] * bb[r];
                    }
                    uint4 o;
                    o.x = packbf(a[0], a[1]); o.y = packbf(a[2], a[3]);
                    o.z = packbf(bb[0], bb[1]); o.w = packbf(bb[2], bb[3]);
                    mp[k][c] = o;
                }
            }
        }

        // flush stats: reduce over the 16 lr lanes, then atomics
#pragma unroll
        for (int s = 0; s < 32; s++) {
            sls[s]  += __shfl_xor(sls[s], 1);  sls[s]  += __shfl_xor(sls[s], 2);
            sls[s]  += __shfl_xor(sls[s], 4);  sls[s]  += __shfl_xor(sls[s], 8);
            sls2[s] += __shfl_xor(sls2[s], 1); sls2[s] += __shfl_xor(sls2[s], 2);
            sls2[s] += __shfl_xor(sls2[s], 4); sls2[s] += __shfl_xor(sls2[s], 8);
        }
        int slot = b & (NSPLIT - 1);
#pragma unroll
        for (int s = 0; s < 32; s++) {
            if (lr == (s & 15)) {
                int col = (s >> 3) * 32 + quad * 8 + ((s >> 2) & 1) * 4 + (s & 3);
                atomicAdd(&stL[slot * 256 + col], sls[s]);
                atomicAdd(&stL[slot * 256 + 128 + col], sls2[s]);
            }
        }
        gbar(cnt, rel, 2 + 2 * l);

        // ---- bn: reduce stats -> coef, apply to register m, update h ----
        if (tid < 256) {
            float s = 0.f;
#pragma unroll 8
            for (int p = 0; p < NSPLIT; p++) s += stL[p * 256 + tid];
            bnls[tid] = s;
        }
        __syncthreads();
        if (tid < 128) {
            float mu = bnls[tid] * (1.f / NN);
            float var = bnls[128 + tid] * (1.f / NN) - mu * mu;
            float a = gamma[l * 128 + tid] * rsqrtf(var + 1e-5f);
            bncf[tid] = a;
            bncf[128 + tid] = beta[l * 128 + tid] - mu * a;
        }
        __syncthreads();
#pragma unroll
        for (int k = 0; k < MAXT; k++) {
            int t = gw + k * 2048;
            if (t < NTILE) {
                int row = t * 16 + lr;
                unsigned short* cp = h + (size_t)row * 128 + quad * 8;
#pragma unroll
                for (int c = 0; c < 4; c++) {
                    uint4 mv = mp[k][c];
                    uint4 hv = *(uint4*)(cp + c * 32);
                    int cb = c * 32 + quad * 8;
                    float4 a0 = *(float4*)&bncf[cb];
                    float4 a1 = *(float4*)&bncf[cb + 4];
                    float4 d0 = *(float4*)&bncf[128 + cb];
                    float4 d1 = *(float4*)&bncf[128 + cb + 4];
                    float h0 = bflo(hv.x) + fmaxf(bflo(mv.x) * a0.x + d0.x, 0.f);
                    float h1 = bfhi(hv.x) + fmaxf(bfhi(mv.x) * a0.y + d0.y, 0.f);
                    float h2 = bflo(hv.y) + fmaxf(bflo(mv.y) * a0.z + d0.z, 0.f);
                    float h3 = bfhi(hv.y) + fmaxf(bfhi(mv.y) * a0.w + d0.w, 0.f);
                    float h4 = bflo(hv.z) + fmaxf(bflo(mv.z) * a1.x + d1.x, 0.f);
                    float h5 = bfhi(hv.z) + fmaxf(bfhi(mv.z) * a1.y + d1.y, 0.f);
                    float h6 = bflo(hv.w) + fmaxf(bflo(mv.w) * a1.z + d1.z, 0.f);
                    float h7 = bfhi(hv.w) + fmaxf(bfhi(mv.w) * a1.w + d1.w, 0.f);
                    uint4 o;
                    o.x = packbf(h0, h1); o.y = packbf(h2, h3);
                    o.z = packbf(h4, h5); o.w = packbf(h6, h7);
                    *(uint4*)(cp + c * 32) = o;
                }
            }
        }
        gbar(cnt, rel, 3 + 2 * l);
    }

    // ---- pool: 4 groups of 128 threads, graphs grid-strided ----
    {
        int sub = tid >> 7, col = tid & 127;
        for (int g = b * 4 + sub; g < NG; g += NBLOCKS * 4) {
            int r0 = gstart[g], r1 = gstart[g + 1];
            float s0 = 0.f, s1 = 0.f;
            int r = r0;
            for (; r + 1 < r1; r += 2) {
                s0 += bf2f(h[(size_t)r * 128 + col]);
                s1 += bf2f(h[(size_t)(r + 1) * 128 + col]);
            }
            if (r < r1) s0 += bf2f(h[(size_t)r * 128 + col]);
            pooled[(size_t)g * 128 + col] = f2bf((s0 + s1) / fmaxf((float)(r1 - r0), 1.f));
        }
    }
    gbar(cnt, rel, 10);

    // ---- gemm: tB = relu(pooled @ Wo1 + bo1)  (standard-layout frags) ----
    {
#pragma unroll
        for (int i = 0; i < 4; i++) {
            int flat = i * 512 + tid;
            ((bf16x8*)Wlds)[flat] = ((const bf16x8*)(Wf + 8 * 16384))[flat];
        }
        __syncthreads();
        if (gw < 313) {
            int rowA = gw * 16 + lr;
            bool rowOK = rowA < NG;
            const unsigned short* ap = pooled + (size_t)rowA * 128 + quad * 8;
            f32x4 acc[8];
#pragma unroll
            for (int c = 0; c < 8; c++) acc[c] = (f32x4){0.f, 0.f, 0.f, 0.f};
#pragma unroll
            for (int kk = 0; kk < 4; kk++) {
                bf16x8 af = rowOK ? *(const bf16x8*)(ap + kk * 32)
                                  : (bf16x8){0, 0, 0, 0, 0, 0, 0, 0};
#pragma unroll
                for (int c = 0; c < 8; c++) {
                    bf16x8 bf = ((const bf16x8*)Wlds)[(c * 4 + kk) * 64 + lane];
                    acc[c] = __builtin_amdgcn_mfma_f32_16x16x32_bf16(af, bf, acc[c], 0, 0, 0);
                }
            }
            int r0 = gw * 16 + quad * 4;
#pragma unroll
            for (int c = 0; c < 8; c++) {
                int col = c * 16 + lr;
                float bv = bo1[col];
#pragma unroll
                for (int r = 0; r < 4; r++) {
                    int row = r0 + r;
                    if (row < NG) tB[(size_t)row * 128 + col] = f2bf(fmaxf(acc[c][r] + bv, 0.f));
                }
            }
        }
    }
    gbar(cnt, rel, 11);

    // ---- outproj: out = tB @ Wo2 + bo2 (both 128-col halves) ----
    {
#pragma unroll
        for (int i = 0; i < 4; i++) {
            int flat = i * 512 + tid;
            ((bf16x8*)Wlds)[flat] = ((const bf16x8*)(Wf + 9 * 16384))[flat];
            ((bf16x8*)Wlds)[2048 + flat] = ((const bf16x8*)(Wf + 10 * 16384))[flat];
        }
        __syncthreads();
        if (gw < 313) {
            int rowA = gw * 16 + lr;
            bool rowOK = rowA < NG;
            const unsigned short* ap = tB + (size_t)rowA * 128 + quad * 8;
            bf16x8 af[4];
#pragma unroll
            for (int kk = 0; kk < 4; kk++)
                af[kk] = rowOK ? *(const bf16x8*)(ap + kk * 32)
                               : (bf16x8){0, 0, 0, 0, 0, 0, 0, 0};
#pragma unroll
            for (int half = 0; half < 2; half++) {
                f32x4 acc[8];
#pragma unroll
                for (int c = 0; c < 8; c++) acc[c] = (f32x4){0.f, 0.f, 0.f, 0.f};
#pragma unroll
                for (int kk = 0; kk < 4; kk++) {
#pragma unroll
                    for (int c = 0; c < 8; c++) {
                        bf16x8 bf = ((const bf16x8*)Wlds)[half * 2048 + (c * 4 + kk) * 64 + lane];
                        acc[c] = __builtin_amdgcn_mfma_f32_16x16x32_bf16(af[kk], bf, acc[c], 0, 0, 0);
                    }
                }
                int r0 = gw * 16 + quad * 4;
#pragma unroll
                for (int c = 0; c < 8; c++) {
                    int col = half * 128 + c * 16 + lr;
                    float bv = bo2[col];
#pragma unroll
                    for (int r = 0; r < 4; r++) {
                        int row = r0 + r;
                        if (row < NG) out[(size_t)row * 256 + col] = acc[c][r] + bv;
                    }
                }
            }
        }
    }
}

extern "C" void kernel_launch(void* const* d_in, const int* in_sizes, int n_in,
                              void* d_out, int out_size, void* d_ws, size_t ws_size,
                              hipStream_t stream) {
    const float* x     = (const float*)d_in[0];
    const int*   ei    = (const int*)d_in[1];
    const int*   batch = (const int*)d_in[2];
    const float* Wn    = (const float*)d_in[3];
    const float* bn_b  = (const float*)d_in[4];
    const float* eps   = (const float*)d_in[5];
    const float* W1    = (const float*)d_in[6];
    const float* b1    = (const float*)d_in[7];
    const float* W2    = (const float*)d_in[8];
    const float* b2    = (const float*)d_in[9];
    const float* gamma = (const float*)d_in[10];
    const float* beta  = (const float*)d_in[11];
    const float* Wo1   = (const float*)d_in[12];
    const float* bo1   = (const float*)d_in[13];
    const float* Wo2   = (const float*)d_in[14];
    const float* bo2   = (const float*)d_in[15];
    float* out = (float*)d_out;
    (void)b2;  // exact cancellation in training-mode BatchNorm

    // ---- workspace ----
    unsigned short* h    = (unsigned short*)d_ws;                  // NN*H bf16
    unsigned short* mScr = h + (size_t)NN * H;                     // CSR transient region
    float* stats4        = (float*)(mScr + (size_t)NN * H);        // 4*NSPLIT*256 floats
    unsigned short* Wf   = (unsigned short*)(stats4 + 4 * NSPLIT * 256); // 11*16384 bf16
    unsigned short* pooledB = Wf + 11 * 16384;                     // NG*H bf16
    unsigned short* tB   = pooledB + (size_t)NG * H;               // NG*H bf16
    int* offsets = (int*)(tB + (size_t)NG * H);                    // NOFF
    int* adj     = offsets + NOFF;                                 // NE
    int* gstart  = adj + NE;                                       // NG+1
    int* bar     = gstart + NG + 1;                                // 2 ints
    // transient CSR-build arrays overlaid in mScr
    int* deg    = (int*)mScr;      // NN
    int* part   = deg + NN;        // NOFF
    int* bsum   = part + NOFF;     // 256
    int* cursor = bsum + 256;      // NN

    setup_k<<<597, 256, 0, stream>>>(batch, W1, W2, Wo1, Wo2, deg, gstart, Wf, bar);
    hist_k<<<2344, 256, 0, stream>>>(ei, deg);
    scan1_k<<<NBLK, 256, 0, stream>>>(deg, part, bsum);
    scan2_k<<<1, 256, 0, stream>>>(bsum);
    scan3_k<<<NBLK, 256, 0, stream>>>(part, bsum, offsets, cursor);
    fill_k<<<2344, 256, 0, stream>>>(ei, cursor, adj);

    fused_k<<<NBLOCKS, 512, 0, stream>>>(x, Wn, bn_b, offsets, adj, eps, b1,
                                         gamma, beta, bo1, bo2, Wf, h, stats4,
                                         pooledB, tB, gstart, out, bar);
}

// Round 4
// 880.409 us; speedup vs baseline: 1.0008x; 1.0008x over previous
//
#include <hip/hip_runtime.h>

#define NN 150000
#define NE 600000
#define NG 5000
#define H 128
#define NOFF (NN + 1)
#define NBLK 147   // ceil(150001 / 1024)
#define NSPLIT 64  // stats_part split factor
#define NTILE 9375 // NN / 16 (exact)
#define NWAVE 2048 // gmlp_k total waves (512 blocks x 4 waves)
#define TREM (NTILE - 4 * NWAVE)  // 1183 waves get 5 tiles

typedef short bf16x8 __attribute__((ext_vector_type(8)));
typedef float f32x4 __attribute__((ext_vector_type(4)));

__device__ __forceinline__ unsigned short f2bf(float f) {
    unsigned u = __builtin_bit_cast(unsigned, f);
    u += 0x7fffu + ((u >> 16) & 1u);
    return (unsigned short)(u >> 16);
}
__device__ __forceinline__ float bf2f(unsigned short u) {
    return __builtin_bit_cast(float, (unsigned)u << 16);
}
__device__ __forceinline__ float bflo(unsigned u) {
    return __builtin_bit_cast(float, u << 16);
}
__device__ __forceinline__ float bfhi(unsigned u) {
    return __builtin_bit_cast(float, u & 0xffff0000u);
}
__device__ __forceinline__ unsigned packbf(float lo, float hi) {
    return (unsigned)f2bf(lo) | ((unsigned)f2bf(hi) << 16);
}

// ---------- fused setup: zero deg + zero stats4 + graph bounds + weight prepack ----------
// W1/W2 fragments (m 0..7) use the PAIRED-PERMUTED column layout for the
// transposed-MFMA gmlp_k: fragment f=2c+h, slot n -> col c*32+(n>>2)*8+h*4+(n&3).
// Wo1/Wo2 (m 8..10) keep the standard layout.
__global__ __launch_bounds__(256) void setup_k(const int* __restrict__ batch,
                                               const float* __restrict__ W1,
                                               const float* __restrict__ W2,
                                               const float* __restrict__ Wo1,
                                               const float* __restrict__ Wo2,
                                               int* __restrict__ deg,
                                               int* __restrict__ gstart,
                                               unsigned short* __restrict__ Wf,
                                               float* __restrict__ stats4) {
    int b = blockIdx.x;
    if (b < 586) {
        int i = b * 256 + threadIdx.x;
        if (i < 4 * NSPLIT * 256) stats4[i] = 0.f;
        if (i < NN) {
            deg[i] = 0;
            int bt = batch[i];
            int prev = (i == 0) ? -1 : batch[i - 1];
            for (int g = prev + 1; g <= bt; g++) gstart[g] = i;
            if (i == NN - 1)
                for (int g = bt + 1; g <= NG; g++) gstart[g] = NN;
        }
        return;
    }
    int m = b - 586;
    const float* W; int ld, col0;
    if (m < 4)       { W = W1 + m * 16384;       ld = 128; col0 = 0; }
    else if (m < 8)  { W = W2 + (m - 4) * 16384; ld = 128; col0 = 0; }
    else if (m == 8) { W = Wo1;                  ld = 128; col0 = 0; }
    else if (m == 9) { W = Wo2;                  ld = 256; col0 = 0; }
    else             { W = Wo2;                  ld = 256; col0 = 128; }
    unsigned short* dst = Wf + m * 16384;
    for (int flat = threadIdx.x; flat < 2048; flat += 256) {
        int c = flat >> 8, kk = (flat >> 6) & 3, lane = flat & 63;
        int ns = lane & 15;
        int n;
        if (m < 8) n = (c >> 1) * 32 + (ns >> 2) * 8 + (c & 1) * 4 + (ns & 3);
        else       n = col0 + c * 16 + ns;
        int k0 = kk * 32 + (lane >> 4) * 8;
        ushort4 lo, hi;
        lo.x = f2bf(W[(size_t)(k0 + 0) * ld + n]);
        lo.y = f2bf(W[(size_t)(k0 + 1) * ld + n]);
        lo.z = f2bf(W[(size_t)(k0 + 2) * ld + n]);
        lo.w = f2bf(W[(size_t)(k0 + 3) * ld + n]);
        hi.x = f2bf(W[(size_t)(k0 + 4) * ld + n]);
        hi.y = f2bf(W[(size_t)(k0 + 5) * ld + n]);
        hi.z = f2bf(W[(size_t)(k0 + 6) * ld + n]);
        hi.w = f2bf(W[(size_t)(k0 + 7) * ld + n]);
        *(ushort4*)&dst[flat * 8]     = lo;
        *(ushort4*)&dst[flat * 8 + 4] = hi;
    }
}

// ---------- encoder + edge histogram fused (block-split) ----------
__global__ __launch_bounds__(256) void enc_hist_k(const float* __restrict__ x,
                                                  const float* __restrict__ Wn,
                                                  const float* __restrict__ bn_b,
                                                  unsigned short* __restrict__ h,
                                                  const int* __restrict__ ei,
                                                  int* __restrict__ deg) {
    int b = blockIdx.x;
    if (b < 18750) {
        int t = b * 256 + threadIdx.x;   // over NN*32
        int i = t >> 5, q = t & 31;
        float4 acc = ((const float4*)bn_b)[q];
#pragma unroll
        for (int k = 0; k < 6; k++) {
            float xv = x[i * 6 + k];
            float4 wv = ((const float4*)Wn)[k * 32 + q];
            acc.x += xv * wv.x; acc.y += xv * wv.y; acc.z += xv * wv.z; acc.w += xv * wv.w;
        }
        ushort4 o;
        o.x = f2bf(acc.x); o.y = f2bf(acc.y); o.z = f2bf(acc.z); o.w = f2bf(acc.w);
        ((ushort4*)h)[t] = o;
    } else {
        int e = (b - 18750) * 256 + threadIdx.x;
        if (e < NE) atomicAdd(&deg[ei[NE + e]], 1);
    }
}

// ---------- CSR build ----------

__global__ __launch_bounds__(256) void scan1_k(const int* __restrict__ deg,
                                               int* __restrict__ part,
                                               int* __restrict__ bsum) {
    __shared__ int ls[256];
    int tid = threadIdx.x;
    int base = blockIdx.x * 1024 + tid * 4;
    int v[4], s = 0;
#pragma unroll
    for (int j = 0; j < 4; j++) {
        int idx = base + j;
        v[j] = (idx < NN) ? deg[idx] : 0;
        s += v[j];
    }
    ls[tid] = s;
    __syncthreads();
    for (int off = 1; off < 256; off <<= 1) {
        int t2 = (tid >= off) ? ls[tid - off] : 0;
        __syncthreads();
        if (tid >= off) ls[tid] += t2;
        __syncthreads();
    }
    int run = ls[tid] - s;
#pragma unroll
    for (int j = 0; j < 4; j++) {
        int idx = base + j;
        if (idx < NOFF) part[idx] = run;
        run += v[j];
    }
    if (tid == 255) bsum[blockIdx.x] = ls[255];
}

// scan2+scan3 fused: each block locally scans the 147 block sums, picks its
// own exclusive prefix, then writes offsets/cursor.
__global__ __launch_bounds__(256) void scan23_k(const int* __restrict__ part,
                                                const int* __restrict__ bsum,
                                                int* __restrict__ offsets,
                                                int* __restrict__ cursor) {
    __shared__ int ls[256];
    __shared__ int bs_sh;
    int tid = threadIdx.x;
    int v = (tid < NBLK) ? bsum[tid] : 0;
    ls[tid] = v;
    __syncthreads();
    for (int off = 1; off < 256; off <<= 1) {
        int t2 = (tid >= off) ? ls[tid - off] : 0;
        __syncthreads();
        if (tid >= off) ls[tid] += t2;
        __syncthreads();
    }
    if (tid == blockIdx.x) bs_sh = ls[tid] - v;   // exclusive prefix for this block
    __syncthreads();
    int bs = bs_sh;
    int base = blockIdx.x * 1024 + tid * 4;
#pragma unroll
    for (int j = 0; j < 4; j++) {
        int idx = base + j;
        if (idx < NOFF) {
            int o = part[idx] + bs;
            offsets[idx] = o;
            if (idx < NN) cursor[idx] = o;
        }
    }
}

__global__ __launch_bounds__(256) void fill_k(const int* __restrict__ ei,
                                              int* __restrict__ cursor,
                                              int* __restrict__ adj) {
    int e = blockIdx.x * 256 + threadIdx.x;
    if (e < NE) {
        int p = atomicAdd(&cursor[ei[NE + e]], 1);
        if (p >= 0 && p < NE) adj[p] = ei[e];
    }
}

// ---------- fused gather + MLP (per layer) ----------
// 512 blocks x 256 threads (4 waves), LDS = 64 KB weights + 4 x 4 KB per-wave
// T scratch = 80 KB -> exactly 2 blocks/CU. Each wave owns a contiguous chunk of
// 4-5 16-row tiles: gather (quarter-wave per row, 16 B/lane, 2x unrolled) writes
// the agg tile into swizzled wave-private LDS T; transposed MFMA (mfma(W,A))
// consumes it; m stored with contiguous 16-B dwordx4 (no partial-line RMW);
// BN stats accumulate in registers, flushed once per wave. b2 dropped (cancels
// in training-mode BatchNorm). No launch_bounds VGPR cap (R3 lesson: spills).
__global__ __launch_bounds__(256) void gmlp_k(const unsigned short* __restrict__ h,
                                              const int* __restrict__ offsets,
                                              const int* __restrict__ adj,
                                              const float* __restrict__ eps, int l,
                                              const unsigned short* __restrict__ Wf1,
                                              const unsigned short* __restrict__ Wf2,
                                              const float* __restrict__ b1,
                                              unsigned short* __restrict__ Cm,
                                              float* __restrict__ stats_part) {
    __shared__ short Wlds[32768];     // W1 frags [0..16383], W2 frags [16384..32767]
    __shared__ short Tlds[4][2048];   // per-wave 16x128 bf16, XOR-swizzled
    int tid = threadIdx.x;
#pragma unroll
    for (int i = 0; i < 8; i++) {
        int flat = i * 256 + tid;
        ((bf16x8*)Wlds)[flat] = ((const bf16x8*)Wf1)[flat];
        ((bf16x8*)Wlds)[2048 + flat] = ((const bf16x8*)Wf2)[flat];
    }
    __syncthreads();

    int w = tid >> 6, lane = tid & 63;
    int quad = lane >> 4, lr = lane & 15;
    short* T = Tlds[w];
    const bf16x8* W1f = (const bf16x8*)Wlds;
    const bf16x8* W2f = (const bf16x8*)(Wlds + 16384);
    float e = 1.f + eps[l];

    // b1 in permuted order: b1p[2*kk+hh][r] = b1[kk*32 + quad*8 + hh*4 + r]
    float4 b1p[8];
#pragma unroll
    for (int c = 0; c < 4; c++) {
        b1p[c * 2]     = ((const float4*)b1)[c * 8 + quad * 2];
        b1p[c * 2 + 1] = ((const float4*)b1)[c * 8 + quad * 2 + 1];
    }

    float sls[32], sls2[32];
#pragma unroll
    for (int s = 0; s < 32; s++) { sls[s] = 0.f; sls2[s] = 0.f; }

    // contiguous tile chunk per wave
    int gw = blockIdx.x * 4 + w;               // 0..2047
    int base = gw * 4 + (gw < TREM ? gw : TREM);
    int cnt = 4 + (gw < TREM ? 1 : 0);
    const uint4* hp = (const uint4*)h;         // row = 16 uint4 (256 B)

    for (int it = 0; it < cnt; it++) {
        int t = base + it;

        // ---- gather 16 rows -> swizzled LDS T (quarter-wave per row) ----
#pragma unroll
        for (int j = 0; j < 4; j++) {
            int i = t * 16 + j * 4 + quad;
            uint4 sv = hp[(size_t)i * 16 + lr];
            float a0 = bflo(sv.x) * e, a1 = bfhi(sv.x) * e;
            float a2 = bflo(sv.y) * e, a3 = bfhi(sv.y) * e;
            float a4 = bflo(sv.z) * e, a5 = bfhi(sv.z) * e;
            float a6 = bflo(sv.w) * e, a7 = bfhi(sv.w) * e;
            float c0 = 0.f, c1 = 0.f, c2 = 0.f, c3 = 0.f;
            float c4 = 0.f, c5 = 0.f, c6 = 0.f, c7 = 0.f;
            int s0 = offsets[i], s1 = offsets[i + 1];
            int kk = s0;
            for (; kk + 1 < s1; kk += 2) {
                int src0 = adj[kk], src1 = adj[kk + 1];
                uint4 v0 = hp[(size_t)src0 * 16 + lr];
                uint4 v1 = hp[(size_t)src1 * 16 + lr];
                a0 += bflo(v0.x); a1 += bfhi(v0.x);
                a2 += bflo(v0.y); a3 += bfhi(v0.y);
                a4 += bflo(v0.z); a5 += bfhi(v0.z);
                a6 += bflo(v0.w); a7 += bfhi(v0.w);
                c0 += bflo(v1.x); c1 += bfhi(v1.x);
                c2 += bflo(v1.y); c3 += bfhi(v1.y);
                c4 += bflo(v1.z); c5 += bfhi(v1.z);
                c6 += bflo(v1.w); c7 += bfhi(v1.w);
            }
            if (kk < s1) {
                uint4 v = hp[(size_t)adj[kk] * 16 + lr];
                a0 += bflo(v.x); a1 += bfhi(v.x);
                a2 += bflo(v.y); a3 += bfhi(v.y);
                a4 += bflo(v.z); a5 += bfhi(v.z);
                a6 += bflo(v.w); a7 += bfhi(v.w);
            }
            a0 += c0; a1 += c1; a2 += c2; a3 += c3;
            a4 += c4; a5 += c5; a6 += c6; a7 += c7;
            uint4 o;
            o.x = packbf(a0, a1); o.y = packbf(a2, a3);
            o.z = packbf(a4, a5); o.w = packbf(a6, a7);
            int rw = j * 4 + quad;
            *(uint4*)&T[((rw << 7) | (lr * 8)) ^ ((rw & 7) << 3)] = o;
        }
        // T is wave-private: no barrier; compiler inserts lgkmcnt before reads.

        // ---- phase 1 (transposed): t = relu(agg @ W1 + b1) ----
        f32x4 acc1[8];
#pragma unroll
        for (int f = 0; f < 8; f++) acc1[f] = (f32x4){0.f, 0.f, 0.f, 0.f};
#pragma unroll
        for (int kk = 0; kk < 4; kk++) {
            bf16x8 af = *(const bf16x8*)&T[((lr << 7) | (kk * 32 + quad * 8)) ^ ((lr & 7) << 3)];
#pragma unroll
            for (int f = 0; f < 8; f++)
                acc1[f] = __builtin_amdgcn_mfma_f32_16x16x32_bf16(
                    W1f[(f * 4 + kk) * 64 + lane], af, acc1[f], 0, 0, 0);
        }
        bf16x8 tf[4];
#pragma unroll
        for (int kk = 0; kk < 4; kk++) {
#pragma unroll
            for (int hh = 0; hh < 2; hh++) {
#pragma unroll
                for (int r = 0; r < 4; r++) {
                    float v = fmaxf(acc1[2 * kk + hh][r] + b1p[2 * kk + hh][r], 0.f);
                    tf[kk][hh * 4 + r] = (short)f2bf(v);
                }
            }
        }

        // ---- phase 2 (transposed): m = t @ W2 (b2 cancels in BatchNorm) ----
        f32x4 acc2[8];
#pragma unroll
        for (int f = 0; f < 8; f++) acc2[f] = (f32x4){0.f, 0.f, 0.f, 0.f};
#pragma unroll
        for (int f = 0; f < 8; f++) {
            acc2[f] = __builtin_amdgcn_mfma_f32_16x16x32_bf16(W2f[(f * 4 + 0) * 64 + lane], tf[0], acc2[f], 0, 0, 0);
            acc2[f] = __builtin_amdgcn_mfma_f32_16x16x32_bf16(W2f[(f * 4 + 1) * 64 + lane], tf[1], acc2[f], 0, 0, 0);
            acc2[f] = __builtin_amdgcn_mfma_f32_16x16x32_bf16(W2f[(f * 4 + 2) * 64 + lane], tf[2], acc2[f], 0, 0, 0);
            acc2[f] = __builtin_amdgcn_mfma_f32_16x16x32_bf16(W2f[(f * 4 + 3) * 64 + lane], tf[3], acc2[f], 0, 0, 0);
        }

        // ---- epilogue: stats (f32, pre-rounding) + 4x 16-B contiguous stores ----
        int row = t * 16 + lr;
        unsigned short* cp = Cm + (size_t)row * 128 + quad * 8;
#pragma unroll
        for (int c = 0; c < 4; c++) {
            f32x4 a = acc2[2 * c], bb = acc2[2 * c + 1];
#pragma unroll
            for (int r = 0; r < 4; r++) {
                sls[(2 * c) * 4 + r]      += a[r];
                sls2[(2 * c) * 4 + r]     += a[r] * a[r];
                sls[(2 * c + 1) * 4 + r]  += bb[r];
                sls2[(2 * c + 1) * 4 + r] += bb[r] * bb[r];
            }
            uint4 o;
            o.x = packbf(a[0], a[1]); o.y = packbf(a[2], a[3]);
            o.z = packbf(bb[0], bb[1]); o.w = packbf(bb[2], bb[3]);
            *(uint4*)(cp + c * 32) = o;
        }
    }

    // flush stats: reduce over the 16 lr lanes, then 2 atomics per (s, owning lane)
#pragma unroll
    for (int s = 0; s < 32; s++) {
        sls[s]  += __shfl_xor(sls[s], 1);  sls[s]  += __shfl_xor(sls[s], 2);
        sls[s]  += __shfl_xor(sls[s], 4);  sls[s]  += __shfl_xor(sls[s], 8);
        sls2[s] += __shfl_xor(sls2[s], 1); sls2[s] += __shfl_xor(sls2[s], 2);
        sls2[s] += __shfl_xor(sls2[s], 4); sls2[s] += __shfl_xor(sls2[s], 8);
    }
    int slot = blockIdx.x & (NSPLIT - 1);
#pragma unroll
    for (int s = 0; s < 32; s++) {
        if (lr == (s & 15)) {
            int col = (s >> 3) * 32 + quad * 8 + ((s >> 2) & 1) * 4 + (s & 3);
            atomicAdd(&stats_part[slot * 256 + col], sls[s]);
            atomicAdd(&stats_part[slot * 256 + 128 + col], sls2[s]);
        }
    }
}

// ---------- bn_apply with inline stats->coef reduce ----------
__global__ __launch_bounds__(256) void bn_apply_k(const unsigned short* __restrict__ m,
                                                  const float* __restrict__ stats_part,
                                                  const float* __restrict__ gamma,
                                                  const float* __restrict__ beta,
                                                  float invN,
                                                  unsigned short* __restrict__ h) {
    __shared__ float ls[256];
    __shared__ float4 caf[32], cbf[32];
    int tid = threadIdx.x;
    float s = 0.f;
    for (int p = 0; p < NSPLIT; p++) s += stats_part[p * 256 + tid];
    ls[tid] = s;
    __syncthreads();
    if (tid < 128) {
        float mu = ls[tid] * invN;
        float var = ls[128 + tid] * invN - mu * mu;
        float a = gamma[tid] * rsqrtf(var + 1e-5f);
        ((float*)caf)[tid] = a;
        ((float*)cbf)[tid] = beta[tid] - mu * a;
    }
    __syncthreads();

    int t0 = blockIdx.x * 256 + tid;
    float4 a = caf[t0 & 31];
    float4 b = cbf[t0 & 31];
    for (int t = t0; t < NN * 32; t += 2048 * 256) {
        ushort4 mv = ((const ushort4*)m)[t];
        ushort4 hv = ((const ushort4*)h)[t];
        float h0 = bf2f(hv.x) + fmaxf(bf2f(mv.x) * a.x + b.x, 0.f);
        float h1 = bf2f(hv.y) + fmaxf(bf2f(mv.y) * a.y + b.y, 0.f);
        float h2 = bf2f(hv.z) + fmaxf(bf2f(mv.z) * a.z + b.z, 0.f);
        float h3 = bf2f(hv.w) + fmaxf(bf2f(mv.w) * a.w + b.w, 0.f);
        ushort4 o;
        o.x = f2bf(h0); o.y = f2bf(h1); o.z = f2bf(h2); o.w = f2bf(h3);
        ((ushort4*)h)[t] = o;
    }
}

// C[M,128] = op(bf16 A[M,128] @ Wf + bias)
template <bool RELU, bool OBF16>
__global__ __launch_bounds__(256) void gemm128f(const unsigned short* __restrict__ A,
                                                const unsigned short* __restrict__ Wf,
                                                const float* __restrict__ bias,
                                                void* __restrict__ Cv, int ldC, int M) {
    __shared__ short Wlds[16384];
    int tid = threadIdx.x;
#pragma unroll
    for (int i = 0; i < 8; i++) {
        int flat = i * 256 + tid;
        ((bf16x8*)Wlds)[flat] = ((const bf16x8*)Wf)[flat];
    }
    __syncthreads();

    int w = tid >> 6, lane = tid & 63;
    int quad = lane >> 4, lr = lane & 15;
    int rowA = blockIdx.x * 64 + w * 16 + lr;
    bool rowOK = rowA < M;
    const unsigned short* ap = A + (size_t)rowA * 128 + quad * 8;

    f32x4 acc[8];
#pragma unroll
    for (int c = 0; c < 8; c++) acc[c] = (f32x4){0.f, 0.f, 0.f, 0.f};
#pragma unroll
    for (int kk = 0; kk < 4; kk++) {
        bf16x8 af = rowOK ? *(const bf16x8*)(ap + kk * 32)
                          : (bf16x8){0, 0, 0, 0, 0, 0, 0, 0};
#pragma unroll
        for (int c = 0; c < 8; c++) {
            bf16x8 bf = ((const bf16x8*)Wlds)[(c * 4 + kk) * 64 + lane];
            acc[c] = __builtin_amdgcn_mfma_f32_16x16x32_bf16(af, bf, acc[c], 0, 0, 0);
        }
    }

    int r0 = blockIdx.x * 64 + w * 16 + quad * 4;
#pragma unroll
    for (int c = 0; c < 8; c++) {
        int col = c * 16 + lr;
        float bv = bias[col];
#pragma unroll
        for (int r = 0; r < 4; r++) {
            int row = r0 + r;
            if (row < M) {
                float v = acc[c][r] + bv;
                if (RELU) v = fmaxf(v, 0.f);
                if (OBF16)
                    ((unsigned short*)Cv)[(size_t)row * ldC + col] = f2bf(v);
                else
                    ((float*)Cv)[(size_t)row * ldC + col] = v;
            }
        }
    }
}

// both Wo2 halves in one launch: blocks [0,79) half 0, [79,158) half 1
__global__ __launch_bounds__(256) void outproj2_k(const unsigned short* __restrict__ A,
                                                  const unsigned short* __restrict__ WfB,
                                                  const float* __restrict__ bo2,
                                                  float* __restrict__ out) {
    __shared__ short Wlds[16384];
    int half = blockIdx.x >= 79;
    int blk = blockIdx.x - half * 79;
    const unsigned short* Wf = WfB + half * 16384;
    int tid = threadIdx.x;
#pragma unroll
    for (int i = 0; i < 8; i++) {
        int flat = i * 256 + tid;
        ((bf16x8*)Wlds)[flat] = ((const bf16x8*)Wf)[flat];
    }
    __syncthreads();

    int w = tid >> 6, lane = tid & 63;
    int quad = lane >> 4, lr = lane & 15;
    int rowA = blk * 64 + w * 16 + lr;
    bool rowOK = rowA < NG;
    const unsigned short* ap = A + (size_t)rowA * 128 + quad * 8;

    f32x4 acc[8];
#pragma unroll
    for (int c = 0; c < 8; c++) acc[c] = (f32x4){0.f, 0.f, 0.f, 0.f};
#pragma unroll
    for (int kk = 0; kk < 4; kk++) {
        bf16x8 af = rowOK ? *(const bf16x8*)(ap + kk * 32)
                          : (bf16x8){0, 0, 0, 0, 0, 0, 0, 0};
#pragma unroll
        for (int c = 0; c < 8; c++) {
            bf16x8 bf = ((const bf16x8*)Wlds)[(c * 4 + kk) * 64 + lane];
            acc[c] = __builtin_amdgcn_mfma_f32_16x16x32_bf16(af, bf, acc[c], 0, 0, 0);
        }
    }

    int r0 = blk * 64 + w * 16 + quad * 4;
#pragma unroll
    for (int c = 0; c < 8; c++) {
        int col = half * 128 + c * 16 + lr;
        float bv = bo2[col];
#pragma unroll
        for (int r = 0; r < 4; r++) {
            int row = r0 + r;
            if (row < NG) out[(size_t)row * 256 + col] = acc[c][r] + bv;
        }
    }
}

// one block per graph: mean over its node rows -> bf16 pooled
__global__ __launch_bounds__(128) void pool_k(const unsigned short* __restrict__ h,
                                              const int* __restrict__ gstart,
                                              unsigned short* __restrict__ pooled) {
    int g = blockIdx.x, col = threadIdx.x;
    int r0 = gstart[g], r1 = gstart[g + 1];
    float s = 0.f;
    for (int r = r0; r < r1; r++) s += bf2f(h[(size_t)r * H + col]);
    pooled[(size_t)g * H + col] = f2bf(s / fmaxf((float)(r1 - r0), 1.f));
}

extern "C" void kernel_launch(void* const* d_in, const int* in_sizes, int n_in,
                              void* d_out, int out_size, void* d_ws, size_t ws_size,
                              hipStream_t stream) {
    const float* x     = (const float*)d_in[0];
    const int*   ei    = (const int*)d_in[1];
    const int*   batch = (const int*)d_in[2];
    const float* Wn    = (const float*)d_in[3];
    const float* bn_b  = (const float*)d_in[4];
    const float* eps   = (const float*)d_in[5];
    const float* W1    = (const float*)d_in[6];
    const float* b1    = (const float*)d_in[7];
    const float* W2    = (const float*)d_in[8];
    const float* b2    = (const float*)d_in[9];
    const float* gamma = (const float*)d_in[10];
    const float* beta  = (const float*)d_in[11];
    const float* Wo1   = (const float*)d_in[12];
    const float* bo1   = (const float*)d_in[13];
    const float* Wo2   = (const float*)d_in[14];
    const float* bo2   = (const float*)d_in[15];
    float* out = (float*)d_out;
    (void)b2;  // exact cancellation in training-mode BatchNorm

    // ---- workspace ----
    unsigned short* h    = (unsigned short*)d_ws;                  // NN*H bf16
    unsigned short* m    = h + (size_t)NN * H;                     // NN*H bf16
    float* stats4        = (float*)(m + (size_t)NN * H);           // 4*NSPLIT*256 floats
    unsigned short* Wf   = (unsigned short*)(stats4 + 4 * NSPLIT * 256); // 11*16384 bf16
    unsigned short* pooledB = Wf + 11 * 16384;                     // NG*H bf16
    unsigned short* tB   = pooledB + (size_t)NG * H;               // NG*H bf16
    int* offsets = (int*)(tB + (size_t)NG * H);                    // NOFF
    int* adj     = offsets + NOFF;                                 // NE
    int* gstart  = adj + NE;                                       // NG+1
    // transient CSR-build arrays overlaid in m (first written by layer-0 gmlp_k)
    int* deg    = (int*)m;         // NN
    int* part   = deg + NN;        // NOFF
    int* bsum   = part + NOFF;     // 256
    int* cursor = bsum + 256;      // NN

    setup_k<<<597, 256, 0, stream>>>(batch, W1, W2, Wo1, Wo2, deg, gstart, Wf, stats4);
    enc_hist_k<<<21094, 256, 0, stream>>>(x, Wn, bn_b, h, ei, deg);
    scan1_k<<<NBLK, 256, 0, stream>>>(deg, part, bsum);
    scan23_k<<<NBLK, 256, 0, stream>>>(part, bsum, offsets, cursor);
    fill_k<<<2344, 256, 0, stream>>>(ei, cursor, adj);

    for (int l = 0; l < 4; l++) {
        gmlp_k<<<512, 256, 0, stream>>>(h, offsets, adj, eps, l,
                                        Wf + l * 16384, Wf + (4 + l) * 16384,
                                        b1 + l * 128, m, stats4 + l * (NSPLIT * 256));
        bn_apply_k<<<2048, 256, 0, stream>>>(m, stats4 + l * (NSPLIT * 256),
                                             gamma + l * 128, beta + l * 128,
                                             1.f / NN, h);
    }

    pool_k<<<NG, 128, 0, stream>>>(h, gstart, pooledB);

    gemm128f<true, true><<<79, 256, 0, stream>>>(
        pooledB, Wf + 8 * 16384, bo1, tB, 128, NG);
    outproj2_k<<<158, 256, 0, stream>>>(tB, Wf + 9 * 16384, bo2, out);
}

// Round 5
// 674.599 us; speedup vs baseline: 1.3061x; 1.3051x over previous
//
#include <hip/hip_runtime.h>

#define NN 150000
#define NE 600000
#define NG 5000
#define H 128
#define NOFF (NN + 1)
#define NBLK 147   // ceil(150001 / 1024)
#define NSPLIT 16  // stats_part split factor
#define NTILE 9375 // NN / 16 (exact)
#define NWAVE 2048 // mlp_k total waves (512 blocks x 4 waves)
#define TREM (NTILE - 4 * NWAVE)  // 1183 waves get 5 tiles

typedef short bf16x8 __attribute__((ext_vector_type(8)));
typedef float f32x4 __attribute__((ext_vector_type(4)));

__device__ __forceinline__ unsigned short f2bf(float f) {
    unsigned u = __builtin_bit_cast(unsigned, f);
    u += 0x7fffu + ((u >> 16) & 1u);
    return (unsigned short)(u >> 16);
}
__device__ __forceinline__ float bf2f(unsigned short u) {
    return __builtin_bit_cast(float, (unsigned)u << 16);
}
__device__ __forceinline__ float bflo(unsigned u) {
    return __builtin_bit_cast(float, u << 16);
}
__device__ __forceinline__ float bfhi(unsigned u) {
    return __builtin_bit_cast(float, u & 0xffff0000u);
}
__device__ __forceinline__ unsigned packbf(float lo, float hi) {
    return (unsigned)f2bf(lo) | ((unsigned)f2bf(hi) << 16);
}

// ---------- fused setup: zero deg + zero stats4 + graph bounds + weight prepack ----------
// W1/W2 fragments (m 0..7) use the PAIRED-PERMUTED column layout for the
// transposed-MFMA mlp_k: fragment f=2c+h, slot n -> col c*32+(n>>2)*8+h*4+(n&3).
// Wo1/Wo2 (m 8..10) keep the standard layout.
__global__ __launch_bounds__(256) void setup_k(const int* __restrict__ batch,
                                               const float* __restrict__ W1,
                                               const float* __restrict__ W2,
                                               const float* __restrict__ Wo1,
                                               const float* __restrict__ Wo2,
                                               int* __restrict__ deg,
                                               int* __restrict__ gstart,
                                               unsigned short* __restrict__ Wf,
                                               float* __restrict__ stats4) {
    int b = blockIdx.x;
    if (b < 586) {
        int i = b * 256 + threadIdx.x;
        if (i < 4 * NSPLIT * 256) stats4[i] = 0.f;
        if (i < NN) {
            deg[i] = 0;
            int bt = batch[i];
            int prev = (i == 0) ? -1 : batch[i - 1];
            for (int g = prev + 1; g <= bt; g++) gstart[g] = i;
            if (i == NN - 1)
                for (int g = bt + 1; g <= NG; g++) gstart[g] = NN;
        }
        return;
    }
    int m = b - 586;
    const float* W; int ld, col0;
    if (m < 4)       { W = W1 + m * 16384;       ld = 128; col0 = 0; }
    else if (m < 8)  { W = W2 + (m - 4) * 16384; ld = 128; col0 = 0; }
    else if (m == 8) { W = Wo1;                  ld = 128; col0 = 0; }
    else if (m == 9) { W = Wo2;                  ld = 256; col0 = 0; }
    else             { W = Wo2;                  ld = 256; col0 = 128; }
    unsigned short* dst = Wf + m * 16384;
    for (int flat = threadIdx.x; flat < 2048; flat += 256) {
        int c = flat >> 8, kk = (flat >> 6) & 3, lane = flat & 63;
        int ns = lane & 15;
        int n;
        if (m < 8) n = (c >> 1) * 32 + (ns >> 2) * 8 + (c & 1) * 4 + (ns & 3);
        else       n = col0 + c * 16 + ns;
        int k0 = kk * 32 + (lane >> 4) * 8;
        ushort4 lo, hi;
        lo.x = f2bf(W[(size_t)(k0 + 0) * ld + n]);
        lo.y = f2bf(W[(size_t)(k0 + 1) * ld + n]);
        lo.z = f2bf(W[(size_t)(k0 + 2) * ld + n]);
        lo.w = f2bf(W[(size_t)(k0 + 3) * ld + n]);
        hi.x = f2bf(W[(size_t)(k0 + 4) * ld + n]);
        hi.y = f2bf(W[(size_t)(k0 + 5) * ld + n]);
        hi.z = f2bf(W[(size_t)(k0 + 6) * ld + n]);
        hi.w = f2bf(W[(size_t)(k0 + 7) * ld + n]);
        *(ushort4*)&dst[flat * 8]     = lo;
        *(ushort4*)&dst[flat * 8 + 4] = hi;
    }
}

// ---------- encoder + edge histogram fused (block-split) ----------
__global__ __launch_bounds__(256) void enc_hist_k(const float* __restrict__ x,
                                                  const float* __restrict__ Wn,
                                                  const float* __restrict__ bn_b,
                                                  unsigned short* __restrict__ h,
                                                  const int* __restrict__ ei,
                                                  int* __restrict__ deg) {
    int b = blockIdx.x;
    if (b < 18750) {
        int t = b * 256 + threadIdx.x;   // over NN*32
        int i = t >> 5, q = t & 31;
        float4 acc = ((const float4*)bn_b)[q];
#pragma unroll
        for (int k = 0; k < 6; k++) {
            float xv = x[i * 6 + k];
            float4 wv = ((const float4*)Wn)[k * 32 + q];
            acc.x += xv * wv.x; acc.y += xv * wv.y; acc.z += xv * wv.z; acc.w += xv * wv.w;
        }
        ushort4 o;
        o.x = f2bf(acc.x); o.y = f2bf(acc.y); o.z = f2bf(acc.z); o.w = f2bf(acc.w);
        ((ushort4*)h)[t] = o;
    } else {
        int e = (b - 18750) * 256 + threadIdx.x;
        if (e < NE) atomicAdd(&deg[ei[NE + e]], 1);
    }
}

// ---------- CSR build ----------

__global__ __launch_bounds__(256) void scan1_k(const int* __restrict__ deg,
                                               int* __restrict__ part,
                                               int* __restrict__ bsum) {
    __shared__ int ls[256];
    int tid = threadIdx.x;
    int base = blockIdx.x * 1024 + tid * 4;
    int v[4], s = 0;
#pragma unroll
    for (int j = 0; j < 4; j++) {
        int idx = base + j;
        v[j] = (idx < NN) ? deg[idx] : 0;
        s += v[j];
    }
    ls[tid] = s;
    __syncthreads();
    for (int off = 1; off < 256; off <<= 1) {
        int t2 = (tid >= off) ? ls[tid - off] : 0;
        __syncthreads();
        if (tid >= off) ls[tid] += t2;
        __syncthreads();
    }
    int run = ls[tid] - s;
#pragma unroll
    for (int j = 0; j < 4; j++) {
        int idx = base + j;
        if (idx < NOFF) part[idx] = run;
        run += v[j];
    }
    if (tid == 255) bsum[blockIdx.x] = ls[255];
}

// scan2+scan3 fused: each block locally scans the 147 block sums, picks its
// own exclusive prefix, then writes offsets/cursor.
__global__ __launch_bounds__(256) void scan23_k(const int* __restrict__ part,
                                                const int* __restrict__ bsum,
                                                int* __restrict__ offsets,
                                                int* __restrict__ cursor) {
    __shared__ int ls[256];
    __shared__ int bs_sh;
    int tid = threadIdx.x;
    int v = (tid < NBLK) ? bsum[tid] : 0;
    ls[tid] = v;
    __syncthreads();
    for (int off = 1; off < 256; off <<= 1) {
        int t2 = (tid >= off) ? ls[tid - off] : 0;
        __syncthreads();
        if (tid >= off) ls[tid] += t2;
        __syncthreads();
    }
    if (tid == blockIdx.x) bs_sh = ls[tid] - v;   // exclusive prefix for this block
    __syncthreads();
    int bs = bs_sh;
    int base = blockIdx.x * 1024 + tid * 4;
#pragma unroll
    for (int j = 0; j < 4; j++) {
        int idx = base + j;
        if (idx < NOFF) {
            int o = part[idx] + bs;
            offsets[idx] = o;
            if (idx < NN) cursor[idx] = o;
        }
    }
}

__global__ __launch_bounds__(256) void fill_k(const int* __restrict__ ei,
                                              int* __restrict__ cursor,
                                              int* __restrict__ adj) {
    int e = blockIdx.x * 256 + threadIdx.x;
    if (e < NE) {
        int p = atomicAdd(&cursor[ei[NE + e]], 1);
        if (p >= 0 && p < NE) adj[p] = ei[e];
    }
}

// ---------- gather: quarter-wave per row, 16 B/lane, 4x unrolled ----------
// 4 independent accumulator sets keep 4 row-reads in flight per quarter-wave
// (16 per wave) to hide L2/L3 latency. VGPR stays low -> high occupancy.
__global__ __launch_bounds__(256) void gather_k(const unsigned short* __restrict__ h,
                                                const int* __restrict__ offsets,
                                                const int* __restrict__ adj,
                                                const float* __restrict__ eps, int l,
                                                unsigned short* __restrict__ agg) {
    int tid = threadIdx.x;
    int wv = tid >> 6, lane = tid & 63;
    int sub = lane >> 4, lr = lane & 15;
    int i = blockIdx.x * 16 + wv * 4 + sub;   // 9375 blocks * 16 rows
    const uint4* hp = (const uint4*)h;        // row = 16 uint4 (256 B)
    float e = 1.f + eps[l];
    uint4 sv = hp[(size_t)i * 16 + lr];
    float a0 = bflo(sv.x) * e, a1 = bfhi(sv.x) * e;
    float a2 = bflo(sv.y) * e, a3 = bfhi(sv.y) * e;
    float a4 = bflo(sv.z) * e, a5 = bfhi(sv.z) * e;
    float a6 = bflo(sv.w) * e, a7 = bfhi(sv.w) * e;
    float b0 = 0.f, b1 = 0.f, b2 = 0.f, b3 = 0.f;
    float b4 = 0.f, b5 = 0.f, b6 = 0.f, b7 = 0.f;
    float c0 = 0.f, c1 = 0.f, c2 = 0.f, c3 = 0.f;
    float c4 = 0.f, c5 = 0.f, c6 = 0.f, c7 = 0.f;
    float d0 = 0.f, d1 = 0.f, d2 = 0.f, d3 = 0.f;
    float d4 = 0.f, d5 = 0.f, d6 = 0.f, d7 = 0.f;
    int s0 = offsets[i], s1 = offsets[i + 1];
    int k = s0;
    for (; k + 3 < s1; k += 4) {
        int src0 = adj[k], src1 = adj[k + 1], src2 = adj[k + 2], src3 = adj[k + 3];
        uint4 v0 = hp[(size_t)src0 * 16 + lr];
        uint4 v1 = hp[(size_t)src1 * 16 + lr];
        uint4 v2 = hp[(size_t)src2 * 16 + lr];
        uint4 v3 = hp[(size_t)src3 * 16 + lr];
        a0 += bflo(v0.x); a1 += bfhi(v0.x);
        a2 += bflo(v0.y); a3 += bfhi(v0.y);
        a4 += bflo(v0.z); a5 += bfhi(v0.z);
        a6 += bflo(v0.w); a7 += bfhi(v0.w);
        b0 += bflo(v1.x); b1 += bfhi(v1.x);
        b2 += bflo(v1.y); b3 += bfhi(v1.y);
        b4 += bflo(v1.z); b5 += bfhi(v1.z);
        b6 += bflo(v1.w); b7 += bfhi(v1.w);
        c0 += bflo(v2.x); c1 += bfhi(v2.x);
        c2 += bflo(v2.y); c3 += bfhi(v2.y);
        c4 += bflo(v2.z); c5 += bfhi(v2.z);
        c6 += bflo(v2.w); c7 += bfhi(v2.w);
        d0 += bflo(v3.x); d1 += bfhi(v3.x);
        d2 += bflo(v3.y); d3 += bfhi(v3.y);
        d4 += bflo(v3.z); d5 += bfhi(v3.z);
        d6 += bflo(v3.w); d7 += bfhi(v3.w);
    }
    for (; k < s1; k++) {
        uint4 v = hp[(size_t)adj[k] * 16 + lr];
        a0 += bflo(v.x); a1 += bfhi(v.x);
        a2 += bflo(v.y); a3 += bfhi(v.y);
        a4 += bflo(v.z); a5 += bfhi(v.z);
        a6 += bflo(v.w); a7 += bfhi(v.w);
    }
    b0 += d0; b1 += d1; b2 += d2; b3 += d3;
    b4 += d4; b5 += d5; b6 += d6; b7 += d7;
    a0 += c0; a1 += c1; a2 += c2; a3 += c3;
    a4 += c4; a5 += c5; a6 += c6; a7 += c7;
    a0 += b0; a1 += b1; a2 += b2; a3 += b3;
    a4 += b4; a5 += b5; a6 += b6; a7 += b7;
    uint4 o;
    o.x = packbf(a0, a1); o.y = packbf(a2, a3);
    o.z = packbf(a4, a5); o.w = packbf(a6, a7);
    ((uint4*)agg)[(size_t)i * 16 + lr] = o;
}

// ---------- persistent transposed-MFMA fused MLP (R2-verified) ----------
// Both phases compute mfma(W_frag, A_frag) -> transposed output: lane (quad,lr)
// holds row lr, cols {c*32+quad*8+h*4+r} (paired-permuted W packing). Phase-1
// output feeds phase-2's B-operand directly from registers (no LDS T buffer).
// Epilogue packs 8 contiguous bf16 -> 16-B dwordx4 stores (no partial-line RMW).
// b2 dropped: exact cancellation in training-mode BatchNorm.
__global__ __launch_bounds__(256) void mlp_k(const unsigned short* __restrict__ A,
                                             const unsigned short* __restrict__ Wf1,
                                             const unsigned short* __restrict__ Wf2,
                                             const float* __restrict__ b1,
                                             unsigned short* __restrict__ Cm,
                                             float* __restrict__ stats_part) {
    __shared__ short Wlds[32768];     // W1 frags [0..16383], W2 frags [16384..32767]
    int tid = threadIdx.x;
#pragma unroll
    for (int i = 0; i < 8; i++) {
        int flat = i * 256 + tid;
        ((bf16x8*)Wlds)[flat] = ((const bf16x8*)Wf1)[flat];
        ((bf16x8*)Wlds)[2048 + flat] = ((const bf16x8*)Wf2)[flat];
    }
    __syncthreads();

    int w = tid >> 6, lane = tid & 63;
    int quad = lane >> 4, lr = lane & 15;
    const bf16x8* W1f = (const bf16x8*)Wlds;
    const bf16x8* W2f = (const bf16x8*)(Wlds + 16384);

    // b1 in permuted order: b1p[2*kk+h][r] = b1[kk*32 + quad*8 + h*4 + r]
    float4 b1p[8];
#pragma unroll
    for (int c = 0; c < 4; c++) {
        b1p[c * 2]     = ((const float4*)b1)[c * 8 + quad * 2];
        b1p[c * 2 + 1] = ((const float4*)b1)[c * 8 + quad * 2 + 1];
    }

    float sls[32], sls2[32];
#pragma unroll
    for (int s = 0; s < 32; s++) { sls[s] = 0.f; sls2[s] = 0.f; }

    // contiguous tile chunk per wave
    int gw = blockIdx.x * 4 + w;               // 0..2047
    int base = gw * 4 + (gw < TREM ? gw : TREM);
    int cnt = 4 + (gw < TREM ? 1 : 0);

    const unsigned short* ap = A + (size_t)(base * 16 + lr) * 128 + quad * 8;
    // prefetch tile 0
    bf16x8 av0 = *(const bf16x8*)(ap);
    bf16x8 av1 = *(const bf16x8*)(ap + 32);
    bf16x8 av2 = *(const bf16x8*)(ap + 64);
    bf16x8 av3 = *(const bf16x8*)(ap + 96);

    for (int it = 0; it < cnt; it++) {
        // issue next tile's loads (wave-uniform branch)
        bf16x8 nv0 = av0, nv1 = av1, nv2 = av2, nv3 = av3;
        if (it + 1 < cnt) {
            const unsigned short* apn = ap + 2048;   // +16 rows
            nv0 = *(const bf16x8*)(apn);
            nv1 = *(const bf16x8*)(apn + 32);
            nv2 = *(const bf16x8*)(apn + 64);
            nv3 = *(const bf16x8*)(apn + 96);
        }

        // phase 1 (transposed): acc1[f][r] = t[lr][(f>>1)*32 + quad*8 + (f&1)*4 + r]
        f32x4 acc1[8];
#pragma unroll
        for (int f = 0; f < 8; f++) acc1[f] = (f32x4){0.f, 0.f, 0.f, 0.f};
#pragma unroll
        for (int f = 0; f < 8; f++) {
            acc1[f] = __builtin_amdgcn_mfma_f32_16x16x32_bf16(W1f[(f * 4 + 0) * 64 + lane], av0, acc1[f], 0, 0, 0);
            acc1[f] = __builtin_amdgcn_mfma_f32_16x16x32_bf16(W1f[(f * 4 + 1) * 64 + lane], av1, acc1[f], 0, 0, 0);
            acc1[f] = __builtin_amdgcn_mfma_f32_16x16x32_bf16(W1f[(f * 4 + 2) * 64 + lane], av2, acc1[f], 0, 0, 0);
            acc1[f] = __builtin_amdgcn_mfma_f32_16x16x32_bf16(W1f[(f * 4 + 3) * 64 + lane], av3, acc1[f], 0, 0, 0);
        }

        // relu(t + b1) -> bf16x8 per kk, straight from registers
        bf16x8 tf[4];
#pragma unroll
        for (int kk = 0; kk < 4; kk++) {
#pragma unroll
            for (int hh = 0; hh < 2; hh++) {
#pragma unroll
                for (int r = 0; r < 4; r++) {
                    float v = fmaxf(acc1[2 * kk + hh][r] + b1p[2 * kk + hh][r], 0.f);
                    tf[kk][hh * 4 + r] = (short)f2bf(v);
                }
            }
        }

        // phase 2 (transposed): acc2[f][r] = m[lr][(f>>1)*32 + quad*8 + (f&1)*4 + r]
        f32x4 acc2[8];
#pragma unroll
        for (int f = 0; f < 8; f++) acc2[f] = (f32x4){0.f, 0.f, 0.f, 0.f};
#pragma unroll
        for (int f = 0; f < 8; f++) {
            acc2[f] = __builtin_amdgcn_mfma_f32_16x16x32_bf16(W2f[(f * 4 + 0) * 64 + lane], tf[0], acc2[f], 0, 0, 0);
            acc2[f] = __builtin_amdgcn_mfma_f32_16x16x32_bf16(W2f[(f * 4 + 1) * 64 + lane], tf[1], acc2[f], 0, 0, 0);
            acc2[f] = __builtin_amdgcn_mfma_f32_16x16x32_bf16(W2f[(f * 4 + 2) * 64 + lane], tf[2], acc2[f], 0, 0, 0);
            acc2[f] = __builtin_amdgcn_mfma_f32_16x16x32_bf16(W2f[(f * 4 + 3) * 64 + lane], tf[3], acc2[f], 0, 0, 0);
        }

        // epilogue: stats (f32, pre-rounding) + 4x 16-B contiguous stores
        int row = (base + it) * 16 + lr;
        unsigned short* cp = Cm + (size_t)row * 128 + quad * 8;
#pragma unroll
        for (int c = 0; c < 4; c++) {
            f32x4 a = acc2[2 * c], b = acc2[2 * c + 1];
#pragma unroll
            for (int r = 0; r < 4; r++) {
                sls[(2 * c) * 4 + r]      += a[r];
                sls2[(2 * c) * 4 + r]     += a[r] * a[r];
                sls[(2 * c + 1) * 4 + r]  += b[r];
                sls2[(2 * c + 1) * 4 + r] += b[r] * b[r];
            }
            uint4 o;
            o.x = packbf(a[0], a[1]); o.y = packbf(a[2], a[3]);
            o.z = packbf(b[0], b[1]); o.w = packbf(b[2], b[3]);
            *(uint4*)(cp + c * 32) = o;
        }

        av0 = nv0; av1 = nv1; av2 = nv2; av3 = nv3;
        ap += 2048;
    }

    // flush stats: reduce over the 16 rows (lr lanes) then 2 atomics per lane
#pragma unroll
    for (int s = 0; s < 32; s++) {
        sls[s]  += __shfl_xor(sls[s], 1);  sls[s]  += __shfl_xor(sls[s], 2);
        sls[s]  += __shfl_xor(sls[s], 4);  sls[s]  += __shfl_xor(sls[s], 8);
        sls2[s] += __shfl_xor(sls2[s], 1); sls2[s] += __shfl_xor(sls2[s], 2);
        sls2[s] += __shfl_xor(sls2[s], 4); sls2[s] += __shfl_xor(sls2[s], 8);
    }
    int slot = blockIdx.x & (NSPLIT - 1);
#pragma unroll
    for (int s = 0; s < 32; s++) {
        if (lr == (s & 15)) {
            int col = (s >> 3) * 32 + quad * 8 + ((s >> 2) & 1) * 4 + (s & 3);
            atomicAdd(&stats_part[slot * 256 + col], sls[s]);
            atomicAdd(&stats_part[slot * 256 + 128 + col], sls2[s]);
        }
    }
}

// ---------- bn_apply with inline stats->coef reduce ----------
__global__ __launch_bounds__(256) void bn_apply_k(const unsigned short* __restrict__ m,
                                                  const float* __restrict__ stats_part,
                                                  const float* __restrict__ gamma,
                                                  const float* __restrict__ beta,
                                                  float invN,
                                                  unsigned short* __restrict__ h) {
    __shared__ float ls[256];
    __shared__ float4 caf[32], cbf[32];
    int tid = threadIdx.x;
    float s = 0.f;
#pragma unroll
    for (int p = 0; p < NSPLIT; p++) s += stats_part[p * 256 + tid];
    ls[tid] = s;
    __syncthreads();
    if (tid < 128) {
        float mu = ls[tid] * invN;
        float var = ls[128 + tid] * invN - mu * mu;
        float a = gamma[tid] * rsqrtf(var + 1e-5f);
        ((float*)caf)[tid] = a;
        ((float*)cbf)[tid] = beta[tid] - mu * a;
    }
    __syncthreads();

    int t0 = blockIdx.x * 256 + tid;
    float4 a = caf[t0 & 31];
    float4 b = cbf[t0 & 31];
    for (int t = t0; t < NN * 32; t += 2048 * 256) {
        ushort4 mv = ((const ushort4*)m)[t];
        ushort4 hv = ((const ushort4*)h)[t];
        float h0 = bf2f(hv.x) + fmaxf(bf2f(mv.x) * a.x + b.x, 0.f);
        float h1 = bf2f(hv.y) + fmaxf(bf2f(mv.y) * a.y + b.y, 0.f);
        float h2 = bf2f(hv.z) + fmaxf(bf2f(mv.z) * a.z + b.z, 0.f);
        float h3 = bf2f(hv.w) + fmaxf(bf2f(mv.w) * a.w + b.w, 0.f);
        ushort4 o;
        o.x = f2bf(h0); o.y = f2bf(h1); o.z = f2bf(h2); o.w = f2bf(h3);
        ((ushort4*)h)[t] = o;
    }
}

// C[M,128] = op(bf16 A[M,128] @ Wf + bias)
template <bool RELU, bool OBF16>
__global__ __launch_bounds__(256) void gemm128f(const unsigned short* __restrict__ A,
                                                const unsigned short* __restrict__ Wf,
                                                const float* __restrict__ bias,
                                                void* __restrict__ Cv, int ldC, int M) {
    __shared__ short Wlds[16384];
    int tid = threadIdx.x;
#pragma unroll
    for (int i = 0; i < 8; i++) {
        int flat = i * 256 + tid;
        ((bf16x8*)Wlds)[flat] = ((const bf16x8*)Wf)[flat];
    }
    __syncthreads();

    int w = tid >> 6, lane = tid & 63;
    int quad = lane >> 4, lr = lane & 15;
    int rowA = blockIdx.x * 64 + w * 16 + lr;
    bool rowOK = rowA < M;
    const unsigned short* ap = A + (size_t)rowA * 128 + quad * 8;

    f32x4 acc[8];
#pragma unroll
    for (int c = 0; c < 8; c++) acc[c] = (f32x4){0.f, 0.f, 0.f, 0.f};
#pragma unroll
    for (int kk = 0; kk < 4; kk++) {
        bf16x8 af = rowOK ? *(const bf16x8*)(ap + kk * 32)
                          : (bf16x8){0, 0, 0, 0, 0, 0, 0, 0};
#pragma unroll
        for (int c = 0; c < 8; c++) {
            bf16x8 bf = ((const bf16x8*)Wlds)[(c * 4 + kk) * 64 + lane];
            acc[c] = __builtin_amdgcn_mfma_f32_16x16x32_bf16(af, bf, acc[c], 0, 0, 0);
        }
    }

    int r0 = blockIdx.x * 64 + w * 16 + quad * 4;
#pragma unroll
    for (int c = 0; c < 8; c++) {
        int col = c * 16 + lr;
        float bv = bias[col];
#pragma unroll
        for (int r = 0; r < 4; r++) {
            int row = r0 + r;
            if (row < M) {
                float v = acc[c][r] + bv;
                if (RELU) v = fmaxf(v, 0.f);
                if (OBF16)
                    ((unsigned short*)Cv)[(size_t)row * ldC + col] = f2bf(v);
                else
                    ((float*)Cv)[(size_t)row * ldC + col] = v;
            }
        }
    }
}

// both Wo2 halves in one launch: blocks [0,79) half 0, [79,158) half 1
__global__ __launch_bounds__(256) void outproj2_k(const unsigned short* __restrict__ A,
                                                  const unsigned short* __restrict__ WfB,
                                                  const float* __restrict__ bo2,
                                                  float* __restrict__ out) {
    __shared__ short Wlds[16384];
    int half = blockIdx.x >= 79;
    int blk = blockIdx.x - half * 79;
    const unsigned short* Wf = WfB + half * 16384;
    int tid = threadIdx.x;
#pragma unroll
    for (int i = 0; i < 8; i++) {
        int flat = i * 256 + tid;
        ((bf16x8*)Wlds)[flat] = ((const bf16x8*)Wf)[flat];
    }
    __syncthreads();

    int w = tid >> 6, lane = tid & 63;
    int quad = lane >> 4, lr = lane & 15;
    int rowA = blk * 64 + w * 16 + lr;
    bool rowOK = rowA < NG;
    const unsigned short* ap = A + (size_t)rowA * 128 + quad * 8;

    f32x4 acc[8];
#pragma unroll
    for (int c = 0; c < 8; c++) acc[c] = (f32x4){0.f, 0.f, 0.f, 0.f};
#pragma unroll
    for (int kk = 0; kk < 4; kk++) {
        bf16x8 af = rowOK ? *(const bf16x8*)(ap + kk * 32)
                          : (bf16x8){0, 0, 0, 0, 0, 0, 0, 0};
#pragma unroll
        for (int c = 0; c < 8; c++) {
            bf16x8 bf = ((const bf16x8*)Wlds)[(c * 4 + kk) * 64 + lane];
            acc[c] = __builtin_amdgcn_mfma_f32_16x16x32_bf16(af, bf, acc[c], 0, 0, 0);
        }
    }

    int r0 = blk * 64 + w * 16 + quad * 4;
#pragma unroll
    for (int c = 0; c < 8; c++) {
        int col = half * 128 + c * 16 + lr;
        float bv = bo2[col];
#pragma unroll
        for (int r = 0; r < 4; r++) {
            int row = r0 + r;
            if (row < NG) out[(size_t)row * 256 + col] = acc[c][r] + bv;
        }
    }
}

// one block per graph: mean over its node rows -> bf16 pooled
__global__ __launch_bounds__(128) void pool_k(const unsigned short* __restrict__ h,
                                              const int* __restrict__ gstart,
                                              unsigned short* __restrict__ pooled) {
    int g = blockIdx.x, col = threadIdx.x;
    int r0 = gstart[g], r1 = gstart[g + 1];
    float s = 0.f;
    for (int r = r0; r < r1; r++) s += bf2f(h[(size_t)r * H + col]);
    pooled[(size_t)g * H + col] = f2bf(s / fmaxf((float)(r1 - r0), 1.f));
}

extern "C" void kernel_launch(void* const* d_in, const int* in_sizes, int n_in,
                              void* d_out, int out_size, void* d_ws, size_t ws_size,
                              hipStream_t stream) {
    const float* x     = (const float*)d_in[0];
    const int*   ei    = (const int*)d_in[1];
    const int*   batch = (const int*)d_in[2];
    const float* Wn    = (const float*)d_in[3];
    const float* bn_b  = (const float*)d_in[4];
    const float* eps   = (const float*)d_in[5];
    const float* W1    = (const float*)d_in[6];
    const float* b1    = (const float*)d_in[7];
    const float* W2    = (const float*)d_in[8];
    const float* b2    = (const float*)d_in[9];
    const float* gamma = (const float*)d_in[10];
    const float* beta  = (const float*)d_in[11];
    const float* Wo1   = (const float*)d_in[12];
    const float* bo1   = (const float*)d_in[13];
    const float* Wo2   = (const float*)d_in[14];
    const float* bo2   = (const float*)d_in[15];
    float* out = (float*)d_out;
    (void)b2;  // exact cancellation in training-mode BatchNorm

    // ---- workspace ----
    unsigned short* h    = (unsigned short*)d_ws;                  // NN*H bf16
    unsigned short* m    = h + (size_t)NN * H;                     // NN*H bf16
    unsigned short* aggB = m + (size_t)NN * H;                     // NN*H bf16
    float* stats4        = (float*)(aggB + (size_t)NN * H);        // 4*NSPLIT*256 floats
    unsigned short* Wf   = (unsigned short*)(stats4 + 4 * NSPLIT * 256); // 11*16384 bf16
    unsigned short* pooledB = Wf + 11 * 16384;                     // NG*H bf16
    unsigned short* tB   = pooledB + (size_t)NG * H;               // NG*H bf16
    int* offsets = (int*)(tB + (size_t)NG * H);                    // NOFF
    int* adj     = offsets + NOFF;                                 // NE
    int* gstart  = adj + NE;                                       // NG+1
    // transient CSR-build arrays overlaid in m (first written by layer-0 mlp_k)
    int* deg    = (int*)m;         // NN
    int* part   = deg + NN;        // NOFF
    int* bsum   = part + NOFF;     // 256
    int* cursor = bsum + 256;      // NN

    setup_k<<<597, 256, 0, stream>>>(batch, W1, W2, Wo1, Wo2, deg, gstart, Wf, stats4);
    enc_hist_k<<<21094, 256, 0, stream>>>(x, Wn, bn_b, h, ei, deg);
    scan1_k<<<NBLK, 256, 0, stream>>>(deg, part, bsum);
    scan23_k<<<NBLK, 256, 0, stream>>>(part, bsum, offsets, cursor);
    fill_k<<<2344, 256, 0, stream>>>(ei, cursor, adj);

    for (int l = 0; l < 4; l++) {
        gather_k<<<9375, 256, 0, stream>>>(h, offsets, adj, eps, l, aggB);
        mlp_k<<<512, 256, 0, stream>>>(aggB, Wf + l * 16384, Wf + (4 + l) * 16384,
                                       b1 + l * 128, m, stats4 + l * (NSPLIT * 256));
        bn_apply_k<<<2048, 256, 0, stream>>>(m, stats4 + l * (NSPLIT * 256),
                                             gamma + l * 128, beta + l * 128,
                                             1.f / NN, h);
    }

    pool_k<<<NG, 128, 0, stream>>>(h, gstart, pooledB);

    gemm128f<true, true><<<79, 256, 0, stream>>>(
        pooledB, Wf + 8 * 16384, bo1, tB, 128, NG);
    outproj2_k<<<158, 256, 0, stream>>>(tB, Wf + 9 * 16384, bo2, out);
}